// Round 1
// baseline (68.626 us; speedup 1.0000x reference)
//
#include <hip/hip_runtime.h>
#include <hip/hip_bf16.h>
#include <cstdint>
#include <cstddef>

#define BB 64
#define SS 2048
#define HH 768
#define LAM 0.0f
#define NEGV -1e30f

// ---------------- Kernel A: scores[b,s] = dot(hidden[b,s,:], w_align[H:2H]) ----
// one wave per (b,s) row; skip rows where mask==0 (their scores are never used)
__global__ void scores_kernel(const float* __restrict__ hidden,
                              const float* __restrict__ token_mask,
                              const float* __restrict__ w_align,
                              float* __restrict__ scores) {
    int row = blockIdx.x * 4 + (threadIdx.x >> 6);   // 4 waves per block
    int lane = threadIdx.x & 63;
    float m = token_mask[(size_t)row * HH];          // broadcast scalar per row
    if (m == 0.0f) return;                           // wave-uniform skip
    const float* hrow = hidden + (size_t)row * HH;
    const float* w2 = w_align + HH;
    float acc = 0.f;
#pragma unroll
    for (int r = 0; r < 3; ++r) {
        int idx = r * 256 + lane * 4;
        float4 h = *reinterpret_cast<const float4*>(hrow + idx);
        float4 w = *reinterpret_cast<const float4*>(w2 + idx);
        acc += h.x * w.x + h.y * w.y + h.z * w.z + h.w * w.w;
    }
#pragma unroll
    for (int off = 32; off >= 1; off >>= 1) acc += __shfl_xor(acc, off);
    if (lane == 0) scores[row] = acc;
}

// ---------------- block reductions (1024 threads, 16 waves) -------------------
__device__ inline float breduce_sum(float v, float* red, int t) {
#pragma unroll
    for (int off = 32; off >= 1; off >>= 1) v += __shfl_xor(v, off);
    if ((t & 63) == 0) red[t >> 6] = v;
    __syncthreads();
    if (t < 16) {
        float x = red[t];
#pragma unroll
        for (int off = 8; off >= 1; off >>= 1) x += __shfl_xor(x, off);
        if (t == 0) red[0] = x;
    }
    __syncthreads();
    float r = red[0];
    __syncthreads();
    return r;
}

__device__ inline float breduce_max(float v, float* red, int t) {
#pragma unroll
    for (int off = 32; off >= 1; off >>= 1) v = fmaxf(v, __shfl_xor(v, off));
    if ((t & 63) == 0) red[t >> 6] = v;
    __syncthreads();
    if (t < 16) {
        float x = red[t];
#pragma unroll
        for (int off = 8; off >= 1; off >>= 1) x = fmaxf(x, __shfl_xor(x, off));
        if (t == 0) red[0] = x;
    }
    __syncthreads();
    float r = red[0];
    __syncthreads();
    return r;
}

// ---------------- Kernel B: per-row sparsegen + pooled sum --------------------
// 64 blocks (one per b), 1024 threads. Faithful replication of reference math.
__global__ __launch_bounds__(1024, 1) void sparsemax_pool_kernel(
        const float* __restrict__ hidden,
        const float* __restrict__ token_mask,
        const float* __restrict__ pooled_tokens,
        const float* __restrict__ w_align,
        const float* __restrict__ b_align,
        const float* __restrict__ scores,
        float* __restrict__ out) {
    __shared__ float zs[SS];      // sort buffer
    __shared__ float csum[SS];    // scan buffer
    __shared__ float pl[SS];      // probs
    __shared__ int   sidx[SS];    // compacted support indices
    __shared__ float spv[SS];     // compacted support probs
    __shared__ float red[32];
    __shared__ int   icnt;

    const int b = blockIdx.x;
    const int t = threadIdx.x;
    const int i0 = t, i1 = t + 1024;

    // --- dotP_b = dot(pooled_tokens[b], w_align[:H]) + b0 ---
    float v = (t < HH) ? pooled_tokens[b * HH + t] * w_align[t] : 0.f;
    float dotP = breduce_sum(v, red, t) + b_align[0];

    // --- load raw scores + validity (mask column 0) ---
    bool valid0 = token_mask[(size_t)(b * SS + i0) * HH] > 0.f;
    bool valid1 = token_mask[(size_t)(b * SS + i1) * HH] > 0.f;
    float s0 = scores[b * SS + i0] + dotP;   // full score (meaningful iff valid)
    float s1 = scores[b * SS + i1] + dotP;

    // --- zmax over valid ---
    float mx = fmaxf(valid0 ? s0 : -INFINITY, valid1 ? s1 : -INFINITY);
    float zmax = breduce_max(mx, red, t);

    // --- n_valid ---
    float nvf = breduce_sum((valid0 ? 1.f : 0.f) + (valid1 ? 1.f : 0.f), red, t);
    int n_valid = (int)(nvf + 0.5f);

    // --- z_sortable ---
    zs[i0] = valid0 ? (s0 - zmax) : NEGV;
    zs[i1] = valid1 ? (s1 - zmax) : NEGV;
    __syncthreads();

    // --- bitonic sort, descending, 2048 elements ---
    for (int k = 2; k <= SS; k <<= 1) {
        for (int j = k >> 1; j > 0; j >>= 1) {
#pragma unroll
            for (int l = 0; l < 2; ++l) {
                int i = t + l * 1024;
                int ixj = i ^ j;
                if (ixj > i) {
                    float a = zs[i], c = zs[ixj];
                    bool desc = ((i & k) == 0);
                    bool sw = desc ? (a < c) : (a > c);
                    if (sw) { zs[i] = c; zs[ixj] = a; }
                }
            }
            __syncthreads();
        }
    }

    // --- zs_m and inclusive scan (Hillis-Steele, in-place with pre-read) ---
    float zm0 = (i0 < n_valid) ? zs[i0] : 0.f;
    float zm1 = (i1 < n_valid) ? zs[i1] : 0.f;
    csum[i0] = zm0;
    csum[i1] = zm1;
    __syncthreads();
    for (int d = 1; d < SS; d <<= 1) {
        float a0 = (i0 >= d) ? csum[i0 - d] : 0.f;
        float a1 = (i1 >= d) ? csum[i1 - d] : 0.f;
        __syncthreads();
        if (i0 >= d) csum[i0] += a0;
        if (i1 >= d) csum[i1] += a1;
        __syncthreads();
    }

    // --- support size k and tau ---
    float ks0 = (float)(i0 + 1), ks1 = (float)(i1 + 1);
    bool g0 = ((1.0f - LAM + ks0 * zm0) > csum[i0]) && (i0 < n_valid);
    bool g1 = ((1.0f - LAM + ks1 * zm1) > csum[i1]) && (i1 < n_valid);
    float kloc = fmaxf(g0 ? ks0 : 0.f, g1 ? ks1 : 0.f);
    float kmax = breduce_max(kloc, red, t);
    float ssum = breduce_sum((g0 ? zm0 : 0.f) + (g1 ? zm1 : 0.f), red, t);
    float kk = fmaxf(kmax, 1.f);
    float tau = (ssum - 1.f + LAM) / kk;

    // --- probs ---
    const float inv = 1.f / (1.f - LAM);
    float p0 = valid0 ? fmaxf((s0 - zmax - tau) * inv, 0.f) : 0.f;
    float p1 = valid1 ? fmaxf((s1 - zmax - tau) * inv, 0.f) : 0.f;
    pl[i0] = p0;
    pl[i1] = p1;
    out[BB * HH + b * SS + i0] = p0;
    out[BB * HH + b * SS + i1] = p1;
    __syncthreads();

    // --- deterministic ballot compaction of the (tiny) support, wave 0 ---
    if (t < 64) {
        int cnt = 0;
        for (int base = 0; base < SS; base += 64) {
            float p = pl[base + t];
            unsigned long long bal = __ballot(p > 0.f);
            if (p > 0.f) {
                int pos = cnt + (int)__popcll(bal & ((1ull << t) - 1ull));
                sidx[pos] = base + t;
                spv[pos] = p;
            }
            cnt += (int)__popcll(bal);
        }
        if (t == 0) icnt = cnt;
    }
    __syncthreads();
    int cnt = icnt;

    // --- pooled[b,h] = sum over support of p * hidden[b,s,h] ---
    if (t < HH) {
        float acc = 0.f;
        for (int j = 0; j < cnt; ++j) {
            acc += spv[j] * hidden[(size_t)(b * SS + sidx[j]) * HH + t];
        }
        out[b * HH + t] = acc;
    }
}

extern "C" void kernel_launch(void* const* d_in, const int* in_sizes, int n_in,
                              void* d_out, int out_size, void* d_ws, size_t ws_size,
                              hipStream_t stream) {
    const float* hidden        = (const float*)d_in[0];
    const float* token_mask    = (const float*)d_in[1];
    const float* pooled_tokens = (const float*)d_in[2];
    const float* w_align       = (const float*)d_in[3];
    const float* b_align       = (const float*)d_in[4];
    float* out = (float*)d_out;

    // scratch for raw scores [B,S]; fall back to the probs region of d_out
    // (it is read before being overwritten within the same block) if ws is small
    float* scores_ws;
    if (ws_size >= (size_t)BB * SS * sizeof(float)) {
        scores_ws = (float*)d_ws;
    } else {
        scores_ws = out + BB * HH;
    }

    scores_kernel<<<dim3((BB * SS) / 4), dim3(256), 0, stream>>>(
        hidden, token_mask, w_align, scores_ws);

    sparsemax_pool_kernel<<<dim3(BB), dim3(1024), 0, stream>>>(
        hidden, token_mask, pooled_tokens, w_align, b_align, scores_ws, out);
}

// Round 2
// 51.248 us; speedup vs baseline: 1.3391x; 1.3391x over previous
//
#include <hip/hip_runtime.h>
#include <hip/hip_bf16.h>
#include <cstdint>
#include <cstddef>

#define BB 64
#define SS 2048
#define HH 768
#define LAM 0.0f
#define NEGV -1e30f

// ---------------- Kernel A: scores[b,s] = dot(hidden[b,s,:], w_align[H:2H]) ----
// one wave per (b,s) row; invalid rows get NEGV sentinel (validity encoded here
// so kernel B never has to re-read the strided token_mask column).
__global__ void scores_kernel(const float* __restrict__ hidden,
                              const float* __restrict__ token_mask,
                              const float* __restrict__ w_align,
                              float* __restrict__ scores) {
    int row = blockIdx.x * 4 + (threadIdx.x >> 6);   // 4 waves per block
    int lane = threadIdx.x & 63;
    float m = token_mask[(size_t)row * HH];          // broadcast scalar per row
    if (m == 0.0f) {
        if (lane == 0) scores[row] = NEGV;
        return;
    }
    const float* hrow = hidden + (size_t)row * HH;
    const float* w2 = w_align + HH;
    float acc = 0.f;
#pragma unroll
    for (int r = 0; r < 3; ++r) {
        int idx = r * 256 + lane * 4;
        float4 h = *reinterpret_cast<const float4*>(hrow + idx);
        float4 w = *reinterpret_cast<const float4*>(w2 + idx);
        acc += h.x * w.x + h.y * w.y + h.z * w.z + h.w * w.w;
    }
#pragma unroll
    for (int off = 32; off >= 1; off >>= 1) acc += __shfl_xor(acc, off);
    if (lane == 0) scores[row] = acc;
}

// ---------------- block reductions (1024 threads, 16 waves) -------------------
__device__ inline float breduce_sum(float v, float* red, int t) {
#pragma unroll
    for (int off = 32; off >= 1; off >>= 1) v += __shfl_xor(v, off);
    if ((t & 63) == 0) red[t >> 6] = v;
    __syncthreads();
    if (t < 16) {
        float x = red[t];
#pragma unroll
        for (int off = 8; off >= 1; off >>= 1) x += __shfl_xor(x, off);
        if (t == 0) red[0] = x;
    }
    __syncthreads();
    float r = red[0];
    __syncthreads();
    return r;
}

__device__ inline float breduce_max(float v, float* red, int t) {
#pragma unroll
    for (int off = 32; off >= 1; off >>= 1) v = fmaxf(v, __shfl_xor(v, off));
    if ((t & 63) == 0) red[t >> 6] = v;
    __syncthreads();
    if (t < 16) {
        float x = red[t];
#pragma unroll
        for (int off = 8; off >= 1; off >>= 1) x = fmaxf(x, __shfl_xor(x, off));
        if (t == 0) red[0] = x;
    }
    __syncthreads();
    float r = red[0];
    __syncthreads();
    return r;
}

// fused (sum, count) reduction for the Newton step
__device__ inline float2 breduce_sum2(float a, float c, float2* red2, int t) {
#pragma unroll
    for (int off = 32; off >= 1; off >>= 1) {
        a += __shfl_xor(a, off);
        c += __shfl_xor(c, off);
    }
    if ((t & 63) == 0) red2[t >> 6] = make_float2(a, c);
    __syncthreads();
    if (t < 16) {
        float2 x = red2[t];
#pragma unroll
        for (int off = 8; off >= 1; off >>= 1) {
            x.x += __shfl_xor(x.x, off);
            x.y += __shfl_xor(x.y, off);
        }
        if (t == 0) red2[0] = x;
    }
    __syncthreads();
    float2 r = red2[0];
    __syncthreads();
    return r;
}

// ---------------- Kernel B: per-row sparsemax via Newton + pooled sum ---------
// 64 blocks (one per b), 1024 threads. tau solves sum(max(z-tau,0)) = 1;
// Newton: tau' = (sum_{z>tau} z - 1)/count_{z>tau}. Monotone, finite, exact.
__global__ __launch_bounds__(1024, 1) void sparsemax_pool_kernel(
        const float* __restrict__ hidden,
        const float* __restrict__ pooled_tokens,
        const float* __restrict__ w_align,
        const float* __restrict__ b_align,
        const float* __restrict__ scores,
        float* __restrict__ out) {
    __shared__ float pl[SS];      // probs (for compaction scan)
    __shared__ int   sidx[SS];    // compacted support indices
    __shared__ float spv[SS];     // compacted support probs
    __shared__ float red[32];
    __shared__ float2 red2[16];
    __shared__ int   icnt;

    const int b = blockIdx.x;
    const int t = threadIdx.x;
    const int i0 = t, i1 = t + 1024;

    // --- dotP_b = dot(pooled_tokens[b], w_align[:H]) + b0 ---
    float v = (t < HH) ? pooled_tokens[b * HH + t] * w_align[t] : 0.f;
    float dotP = breduce_sum(v, red, t) + b_align[0];

    // --- raw scores (NEGV sentinel == invalid) ---
    float r0 = scores[b * SS + i0];
    float r1 = scores[b * SS + i1];
    bool valid0 = r0 > -1e29f;
    bool valid1 = r1 > -1e29f;
    float s0 = r0 + dotP;
    float s1 = r1 + dotP;

    // --- zmax over valid ---
    float mx = fmaxf(valid0 ? s0 : -INFINITY, valid1 ? s1 : -INFINITY);
    float zmax = breduce_max(mx, red, t);

    float z0 = valid0 ? (s0 - zmax) : NEGV;   // max valid z is exactly 0
    float z1 = valid1 ? (s1 - zmax) : NEGV;

    // --- Newton iteration on f(tau) = sum(max(z-tau,0)) - 1 ---
    // start at tau = -1 (= zmax-1): f >= 0, count >= 1; tau* < 0 so the max
    // element always stays active -> count never 0.
    float tau = -1.0f;
#pragma unroll 1
    for (int it = 0; it < 50; ++it) {
        float a = (z0 > tau ? z0 : 0.f) + (z1 > tau ? z1 : 0.f);
        float c = (z0 > tau ? 1.f : 0.f) + (z1 > tau ? 1.f : 0.f);
        float2 sc = breduce_sum2(a, c, red2, t);
        float tn = (sc.x - 1.f + LAM) / sc.y;
        if (tn == tau) break;        // block-uniform: tau is uniform
        tau = tn;
    }

    // --- probs ---
    const float inv = 1.f / (1.f - LAM);
    float p0 = valid0 ? fmaxf((z0 - tau) * inv, 0.f) : 0.f;
    float p1 = valid1 ? fmaxf((z1 - tau) * inv, 0.f) : 0.f;
    pl[i0] = p0;
    pl[i1] = p1;
    out[BB * HH + b * SS + i0] = p0;
    out[BB * HH + b * SS + i1] = p1;
    __syncthreads();

    // --- deterministic ballot compaction of the (tiny) support, wave 0 ---
    if (t < 64) {
        int cnt = 0;
        for (int base = 0; base < SS; base += 64) {
            float p = pl[base + t];
            unsigned long long bal = __ballot(p > 0.f);
            if (p > 0.f) {
                int pos = cnt + (int)__popcll(bal & ((1ull << t) - 1ull));
                sidx[pos] = base + t;
                spv[pos] = p;
            }
            cnt += (int)__popcll(bal);
        }
        if (t == 0) icnt = cnt;
    }
    __syncthreads();
    int cnt = icnt;

    // --- pooled[b,h] = sum over support of p * hidden[b,s,h] ---
    if (t < HH) {
        float acc = 0.f;
        for (int j = 0; j < cnt; ++j) {
            acc += spv[j] * hidden[(size_t)(b * SS + sidx[j]) * HH + t];
        }
        out[b * HH + t] = acc;
    }
}

extern "C" void kernel_launch(void* const* d_in, const int* in_sizes, int n_in,
                              void* d_out, int out_size, void* d_ws, size_t ws_size,
                              hipStream_t stream) {
    const float* hidden        = (const float*)d_in[0];
    const float* token_mask    = (const float*)d_in[1];
    const float* pooled_tokens = (const float*)d_in[2];
    const float* b_align       = (const float*)d_in[4];
    const float* w_align       = (const float*)d_in[3];
    float* out = (float*)d_out;

    // scratch for raw scores [B,S]; fall back to the probs region of d_out
    // (read before overwritten within the same block) if ws is too small
    float* scores_ws;
    if (ws_size >= (size_t)BB * SS * sizeof(float)) {
        scores_ws = (float*)d_ws;
    } else {
        scores_ws = out + BB * HH;
    }

    scores_kernel<<<dim3((BB * SS) / 4), dim3(256), 0, stream>>>(
        hidden, token_mask, w_align, scores_ws);

    sparsemax_pool_kernel<<<dim3(BB), dim3(1024), 0, stream>>>(
        hidden, pooled_tokens, w_align, b_align, scores_ws, out);
}

// Round 3
// 49.375 us; speedup vs baseline: 1.3899x; 1.0379x over previous
//
#include <hip/hip_runtime.h>
#include <hip/hip_bf16.h>
#include <cstdint>
#include <cstddef>

#define BB 64
#define SS 2048
#define HH 768
#define LAM 0.0f
#define NEGV -1e30f

// ---------------- Kernel A: scores[b,s] = dot(hidden[b,s,:], w_align[H:2H]) ----
// one wave per (b,s) row; invalid rows get NEGV sentinel (validity encoded here
// so kernel B never re-reads the strided token_mask column).
__global__ void scores_kernel(const float* __restrict__ hidden,
                              const float* __restrict__ token_mask,
                              const float* __restrict__ w_align,
                              float* __restrict__ scores) {
    int row = blockIdx.x * 4 + (threadIdx.x >> 6);   // 4 waves per block
    int lane = threadIdx.x & 63;
    float m = token_mask[(size_t)row * HH];          // broadcast scalar per row
    if (m == 0.0f) {
        if (lane == 0) scores[row] = NEGV;
        return;
    }
    const float* hrow = hidden + (size_t)row * HH;
    const float* w2 = w_align + HH;
    float acc = 0.f;
#pragma unroll
    for (int r = 0; r < 3; ++r) {
        int idx = r * 256 + lane * 4;
        float4 h = *reinterpret_cast<const float4*>(hrow + idx);
        float4 w = *reinterpret_cast<const float4*>(w2 + idx);
        acc += h.x * w.x + h.y * w.y + h.z * w.z + h.w * w.w;
    }
#pragma unroll
    for (int off = 32; off >= 1; off >>= 1) acc += __shfl_xor(acc, off);
    if (lane == 0) scores[row] = acc;
}

// ---------------- Kernel B: one wave per batch row --------------------------
// 16 blocks x 256 threads (4 waves); wave w owns row b = global wave id.
// All state in registers: z[32] per lane covers S=2048. No LDS, no barriers.
__global__ __launch_bounds__(256, 1) void tau_pool_kernel(
        const float* __restrict__ hidden,
        const float* __restrict__ pooled_tokens,
        const float* __restrict__ w_align,
        const float* __restrict__ b_align,
        const float* __restrict__ scores,
        float* __restrict__ out) {
    const int b = (blockIdx.x * 256 + threadIdx.x) >> 6;   // 0..63
    const int lane = threadIdx.x & 63;

    // --- dotP = dot(pooled_tokens[b], w_align[:H]) + b0 (in-wave) ---
    const float* pt = pooled_tokens + b * HH;
    float dp = 0.f;
#pragma unroll
    for (int i = 0; i < 3; ++i) {
        int idx = i * 256 + lane * 4;
        float4 a = *reinterpret_cast<const float4*>(pt + idx);
        float4 w = *reinterpret_cast<const float4*>(w_align + idx);
        dp += a.x * w.x + a.y * w.y + a.z * w.z + a.w * w.w;
    }
#pragma unroll
    for (int off = 32; off >= 1; off >>= 1) dp += __shfl_xor(dp, off);
    dp += b_align[0];

    // --- load scores: element e = i*256 + lane*4 + c  ->  z[i*4+c] ---
    const float* sc = scores + b * SS;
    float z[32];
#pragma unroll
    for (int i = 0; i < 8; ++i) {
        float4 v = *reinterpret_cast<const float4*>(sc + i * 256 + lane * 4);
        z[i * 4 + 0] = v.x + dp;   // invalid rows stay ~ -1e30 (sentinel survives)
        z[i * 4 + 1] = v.y + dp;
        z[i * 4 + 2] = v.z + dp;
        z[i * 4 + 3] = v.w + dp;
    }

    // --- zmax (invalid never wins; >=16 valid guaranteed) ---
    float mx = z[0];
#pragma unroll
    for (int i = 1; i < 32; ++i) mx = fmaxf(mx, z[i]);
#pragma unroll
    for (int off = 32; off >= 1; off >>= 1) mx = fmaxf(mx, __shfl_xor(mx, off));
#pragma unroll
    for (int i = 0; i < 32; ++i) z[i] -= mx;   // max valid z == 0; invalid ~ -1e30

    // --- Newton on f(tau) = sum(max(z-tau,0)) - 1; tau' = (sum_act - 1)/cnt_act.
    // Start tau=-1: f>=0 (max element contributes 1). tau* < 0 so max element
    // always active -> count never 0. Monotone, exact on convergence.
    float tau = -1.0f;
#pragma unroll 1
    for (int it = 0; it < 50; ++it) {
        float a = 0.f, c = 0.f;
#pragma unroll
        for (int i = 0; i < 32; ++i) {
            bool g = z[i] > tau;
            a += g ? z[i] : 0.f;
            c += g ? 1.f : 0.f;
        }
#pragma unroll
        for (int off = 32; off >= 1; off >>= 1) {
            a += __shfl_xor(a, off);
            c += __shfl_xor(c, off);
        }
        float tn = (a - 1.f + LAM) / c;
        if (tn == tau) break;          // wave-uniform
        tau = tn;
    }

    // --- probs: compute, write coalesced float4 ---
    const float inv = 1.f / (1.f - LAM);
    float p[32];
#pragma unroll
    for (int i = 0; i < 32; ++i) p[i] = fmaxf((z[i] - tau) * inv, 0.f);
    float* po = out + BB * HH + b * SS;
#pragma unroll
    for (int i = 0; i < 8; ++i) {
        float4 v = make_float4(p[i * 4 + 0], p[i * 4 + 1], p[i * 4 + 2], p[i * 4 + 3]);
        *reinterpret_cast<float4*>(po + i * 256 + lane * 4) = v;
    }

    // --- pooled[b,h] = sum over support of p * hidden[b,s,h] ---
    // support iterated via ballot bit-scan + shuffle broadcast; no LDS.
    float acc[12];
#pragma unroll
    for (int j = 0; j < 12; ++j) acc[j] = 0.f;
    const float* hb = hidden + (size_t)b * SS * HH;
#pragma unroll 1
    for (int i = 0; i < 8; ++i) {
#pragma unroll 1
        for (int c = 0; c < 4; ++c) {
            float pv = p[i * 4 + c];
            unsigned long long m = __ballot(pv > 0.f);
            while (m) {
                int src = __ffsll((long long)m) - 1;
                m &= m - 1;
                float pb = __shfl(pv, src);
                int sidx = i * 256 + src * 4 + c;
                const float* hrow = hb + (size_t)sidx * HH;
#pragma unroll
                for (int j = 0; j < 12; ++j)
                    acc[j] += pb * hrow[j * 64 + lane];
            }
        }
    }
#pragma unroll
    for (int j = 0; j < 12; ++j)
        out[b * HH + j * 64 + lane] = acc[j];
}

extern "C" void kernel_launch(void* const* d_in, const int* in_sizes, int n_in,
                              void* d_out, int out_size, void* d_ws, size_t ws_size,
                              hipStream_t stream) {
    const float* hidden        = (const float*)d_in[0];
    const float* token_mask    = (const float*)d_in[1];
    const float* pooled_tokens = (const float*)d_in[2];
    const float* w_align       = (const float*)d_in[3];
    const float* b_align       = (const float*)d_in[4];
    float* out = (float*)d_out;

    // scratch for raw scores [B,S]; fall back to the probs region of d_out
    // (read before overwritten by the same wave) if ws is too small
    float* scores_ws;
    if (ws_size >= (size_t)BB * SS * sizeof(float)) {
        scores_ws = (float*)d_ws;
    } else {
        scores_ws = out + BB * HH;
    }

    scores_kernel<<<dim3((BB * SS) / 4), dim3(256), 0, stream>>>(
        hidden, token_mask, w_align, scores_ws);

    tau_pool_kernel<<<dim3(16), dim3(256), 0, stream>>>(
        hidden, pooled_tokens, w_align, b_align, scores_ws, out);
}

// Round 4
// 47.180 us; speedup vs baseline: 1.4546x; 1.0465x over previous
//
#include <hip/hip_runtime.h>
#include <hip/hip_bf16.h>
#include <cstdint>
#include <cstddef>

#define BB 64
#define SS 2048
#define HH 768
#define LAM 0.0f
#define NEGV -1e30f

// ---------------- Kernel A: scores[b,s] = dot(hidden[b,s,:], w_align[H:2H]) ----
// one wave per (b,s) row; invalid rows get NEGV sentinel (validity encoded here
// so kernel B never re-reads the strided token_mask column).
__global__ void scores_kernel(const float* __restrict__ hidden,
                              const float* __restrict__ token_mask,
                              const float* __restrict__ w_align,
                              float* __restrict__ scores) {
    int row = blockIdx.x * 4 + (threadIdx.x >> 6);   // 4 waves per block
    int lane = threadIdx.x & 63;
    float m = token_mask[(size_t)row * HH];          // broadcast scalar per row
    if (m == 0.0f) {
        if (lane == 0) scores[row] = NEGV;
        return;
    }
    const float* hrow = hidden + (size_t)row * HH;
    const float* w2 = w_align + HH;
    float acc = 0.f;
#pragma unroll
    for (int r = 0; r < 3; ++r) {
        int idx = r * 256 + lane * 4;
        float4 h = *reinterpret_cast<const float4*>(hrow + idx);
        float4 w = *reinterpret_cast<const float4*>(w2 + idx);
        acc += h.x * w.x + h.y * w.y + h.z * w.z + h.w * w.w;
    }
#pragma unroll
    for (int off = 32; off >= 1; off >>= 1) acc += __shfl_xor(acc, off);
    if (lane == 0) scores[row] = acc;
}

// ---------------- Kernel B: one block per batch row ---------------------------
// 64 blocks x 768 threads (12 waves). Wave 0: Newton tau (all state in its
// registers, z[32]/lane), probs write, ballot-compaction of support into LDS.
// Barrier. Then all 12 waves gather pooled[b,h] with thread<->h mapping,
// 4 support rows in flight per iteration.
__global__ __launch_bounds__(768, 1) void tau_pool_kernel(
        const float* __restrict__ hidden,
        const float* __restrict__ pooled_tokens,
        const float* __restrict__ w_align,
        const float* __restrict__ b_align,
        const float* __restrict__ scores,
        float* __restrict__ out) {
    __shared__ int   s_idx[SS];
    __shared__ float s_p[SS];
    __shared__ int   s_cnt;

    const int b = blockIdx.x;
    const int t = threadIdx.x;
    const int lane = t & 63;
    const int wv = t >> 6;

    if (wv == 0) {
        // --- dotP = dot(pooled_tokens[b], w_align[:H]) + b0 ---
        const float* pt = pooled_tokens + b * HH;
        float dp = 0.f;
#pragma unroll
        for (int i = 0; i < 3; ++i) {
            int idx = i * 256 + lane * 4;
            float4 a = *reinterpret_cast<const float4*>(pt + idx);
            float4 w = *reinterpret_cast<const float4*>(w_align + idx);
            dp += a.x * w.x + a.y * w.y + a.z * w.z + a.w * w.w;
        }
#pragma unroll
        for (int off = 32; off >= 1; off >>= 1) dp += __shfl_xor(dp, off);
        dp += b_align[0];

        // --- load scores: element e = i*256 + lane*4 + c -> z[i*4+c] ---
        const float* sc = scores + b * SS;
        float z[32];
#pragma unroll
        for (int i = 0; i < 8; ++i) {
            float4 v = *reinterpret_cast<const float4*>(sc + i * 256 + lane * 4);
            z[i * 4 + 0] = v.x + dp;   // NEGV sentinel survives +dp
            z[i * 4 + 1] = v.y + dp;
            z[i * 4 + 2] = v.z + dp;
            z[i * 4 + 3] = v.w + dp;
        }

        // --- zmax over valid (invalid ~ -1e30 never wins) ---
        float mx = z[0];
#pragma unroll
        for (int i = 1; i < 32; ++i) mx = fmaxf(mx, z[i]);
#pragma unroll
        for (int off = 32; off >= 1; off >>= 1) mx = fmaxf(mx, __shfl_xor(mx, off));
#pragma unroll
        for (int i = 0; i < 32; ++i) z[i] -= mx;

        // --- Newton on f(tau) = sum(max(z-tau,0)) - 1 ---
        // tau0=-1: f>=0; f convex decreasing => monotone increase, active set
        // monotone shrink, exact on stabilization. Count never 0 (max stays in).
        float tau = -1.0f;
#pragma unroll 1
        for (int it = 0; it < 50; ++it) {
            float a = 0.f, c = 0.f;
#pragma unroll
            for (int i = 0; i < 32; ++i) {
                bool g = z[i] > tau;
                a += g ? z[i] : 0.f;
                c += g ? 1.f : 0.f;
            }
#pragma unroll
            for (int off = 32; off >= 1; off >>= 1) {
                a += __shfl_xor(a, off);
                c += __shfl_xor(c, off);
            }
            float tn = (a - 1.f + LAM) / c;
            if (tn == tau) break;      // wave-uniform
            tau = tn;
        }

        // --- probs: write coalesced float4, compact support into LDS ---
        const float inv = 1.f / (1.f - LAM);
        float p[32];
#pragma unroll
        for (int i = 0; i < 32; ++i) p[i] = fmaxf((z[i] - tau) * inv, 0.f);
        float* po = out + BB * HH + b * SS;
#pragma unroll
        for (int i = 0; i < 8; ++i) {
            float4 v = make_float4(p[i * 4 + 0], p[i * 4 + 1], p[i * 4 + 2], p[i * 4 + 3]);
            *reinterpret_cast<float4*>(po + i * 256 + lane * 4) = v;
        }

        int cnt = 0;
#pragma unroll
        for (int i = 0; i < 8; ++i) {
#pragma unroll
            for (int c = 0; c < 4; ++c) {
                float pv = p[i * 4 + c];
                unsigned long long m = __ballot(pv > 0.f);
                if (pv > 0.f) {
                    int pos = cnt + (int)__popcll(m & ((1ull << lane) - 1ull));
                    s_idx[pos] = i * 256 + lane * 4 + c;
                    s_p[pos] = pv;
                }
                cnt += (int)__popcll(m);
            }
        }
        if (lane == 0) s_cnt = cnt;
    }
    __syncthreads();

    // --- pooled[b,h]: all 12 waves, thread t <-> column h=t, 4 rows in flight -
    const int cnt = s_cnt;
    const float* hb = hidden + (size_t)b * SS * HH;
    float acc = 0.f;
#pragma unroll 1
    for (int j = 0; j < cnt; j += 4) {
        int   i0 = s_idx[j];
        float p0 = s_p[j];
        int   i1 = (j + 1 < cnt) ? s_idx[j + 1] : 0;
        float p1 = (j + 1 < cnt) ? s_p[j + 1] : 0.f;
        int   i2 = (j + 2 < cnt) ? s_idx[j + 2] : 0;
        float p2 = (j + 2 < cnt) ? s_p[j + 2] : 0.f;
        int   i3 = (j + 3 < cnt) ? s_idx[j + 3] : 0;
        float p3 = (j + 3 < cnt) ? s_p[j + 3] : 0.f;
        float h0 = hb[(size_t)i0 * HH + t];
        float h1 = hb[(size_t)i1 * HH + t];
        float h2 = hb[(size_t)i2 * HH + t];
        float h3 = hb[(size_t)i3 * HH + t];
        acc += p0 * h0 + p1 * h1 + p2 * h2 + p3 * h3;
    }
    out[b * HH + t] = acc;
}

extern "C" void kernel_launch(void* const* d_in, const int* in_sizes, int n_in,
                              void* d_out, int out_size, void* d_ws, size_t ws_size,
                              hipStream_t stream) {
    const float* hidden        = (const float*)d_in[0];
    const float* token_mask    = (const float*)d_in[1];
    const float* pooled_tokens = (const float*)d_in[2];
    const float* w_align       = (const float*)d_in[3];
    const float* b_align       = (const float*)d_in[4];
    float* out = (float*)d_out;

    // scratch for raw scores [B,S]; fall back to the probs region of d_out
    // (wave 0 reads the full row into registers before overwriting it) if ws
    // is too small
    float* scores_ws;
    if (ws_size >= (size_t)BB * SS * sizeof(float)) {
        scores_ws = (float*)d_ws;
    } else {
        scores_ws = out + BB * HH;
    }

    scores_kernel<<<dim3((BB * SS) / 4), dim3(256), 0, stream>>>(
        hidden, token_mask, w_align, scores_ws);

    tau_pool_kernel<<<dim3(BB), dim3(768), 0, stream>>>(
        hidden, pooled_tokens, w_align, b_align, scores_ws, out);
}